// Round 6
// baseline (446.859 us; speedup 1.0000x reference)
//
#include <hip/hip_runtime.h>
#include <math.h>

#define N_ROWS 16384
#define VOCAB  8192
#define EMB    256

// ---- MFMA path tiling (m97-shaped: 128x128 tile, BK=32, 4x4 acc/wave) ----
#define BM 128
#define BV 128
#define BK 32                      // halfs per K-step
#define VSPLIT 8                   // grid (128, 8)
#define VRANGE (VOCAB / VSPLIT)    // 1024
#define NVT    (VRANGE / BV)       // 8
#define LW 32                      // LDS row stride in halfs (64 B) — UNPADDED (global_load_lds)
#define TAU 0.15f                  // rescue margin: >= 2*max|dist err| (~0.107 at 4.2 sigma)

typedef _Float16 half8 __attribute__((ext_vector_type(8)));
typedef _Float16 half4 __attribute__((ext_vector_type(4)));
typedef float floatx4 __attribute__((ext_vector_type(4)));

// async global->LDS DMA, 16 B/lane; LDS dest = wave-uniform base + lane*16
__device__ __forceinline__ void load_lds16(const _Float16* g, _Float16* l) {
    __builtin_amdgcn_global_load_lds(
        (const __attribute__((address_space(1))) void*)g,
        (__attribute__((address_space(3))) void*)l, 16, 0, 0);
}

// ---------------------------------------------------------------------------
// esq[v] = ||cb[v]||^2 (fp32, exact). One wave per row.
// ---------------------------------------------------------------------------
__global__ void esq_kernel(const float* __restrict__ cb, float* __restrict__ esq) {
    const int wave = threadIdx.x >> 6;
    const int lane = threadIdx.x & 63;
    const int row  = blockIdx.x * 4 + wave;
    const float4 v = *(const float4*)(cb + (size_t)row * EMB + lane * 4);
    float s = v.x * v.x + v.y * v.y + v.z * v.z + v.w * v.w;
    #pragma unroll
    for (int off = 32; off > 0; off >>= 1) s += __shfl_down(s, off, 64);
    if (lane == 0) esq[row] = s;
}

// ---------------------------------------------------------------------------
// Convert fp32 -> fp16 (single precision level; rescue covers the error).
// ---------------------------------------------------------------------------
__global__ void split_kernel(const float* __restrict__ z, const float* __restrict__ cb,
                             _Float16* __restrict__ zh, _Float16* __restrict__ ch) {
    const size_t gid = (size_t)blockIdx.x * blockDim.x + threadIdx.x;
    const size_t ZQ4 = (size_t)N_ROWS * EMB / 4;
    const float* src; _Float16* dst; size_t idx4;
    if (gid < ZQ4) { src = z;  dst = zh; idx4 = gid; }
    else           { src = cb; dst = ch; idx4 = gid - ZQ4; }
    const float4 f = *(const float4*)(src + idx4 * 4);
    half4 h;
    h.x = (_Float16)f.x; h.y = (_Float16)f.y; h.z = (_Float16)f.z; h.w = (_Float16)f.w;
    *(half4*)(dst + idx4 * 4) = h;
}

// ---------------------------------------------------------------------------
// MFMA dist kernel, single fp16 term: acc = Zh*Ch^T; dist~ = esq - 2*acc.
// Staging: global_load_lds dwordx4 into unpadded [row][32-half] tiles
// (frag reads hit all 32 banks uniformly: start bank = 16*(lr&1)+4*quad).
// Per-lane deferred top-2 over its 16 rows; ONE cross-lane reduce at end.
// Ties/margins < TAU are resolved exactly by the rescue pass, so approx
// tie-break order is irrelevant.
// ---------------------------------------------------------------------------
__global__ __launch_bounds__(256, 3)
void mfma_dist_kernel(const _Float16* __restrict__ zh, const _Float16* __restrict__ ch,
                      const float* __restrict__ esq,
                      float* __restrict__ pd1, int* __restrict__ pi1,
                      float* __restrict__ pd2) {
    __shared__ _Float16 zs[BM * LW];   // 8 KB
    __shared__ _Float16 cs[BV * LW];   // 8 KB
    // end-phase scratch aliases zs (3 KB, used only after the vt loop)
    float* sc_d1 = (float*)zs;                 // [BM][2]
    float* sc_d2 = sc_d1 + BM * 2;
    int*   sc_i1 = (int*)(sc_d2 + BM * 2);

    const int row0  = blockIdx.x * BM;
    const int vbase = blockIdx.y * VRANGE;

    const int tid  = threadIdx.x;
    const int w    = tid >> 6;
    const int lane = tid & 63;
    const int lr   = lane & 15;          // frag row / C col
    const int quad = lane >> 4;          // 0..3
    const int mh   = (w >> 1) * 64;      // wave m-origin
    const int vh   = (w & 1) * 64;       // wave v-origin

    // staging: wave w covers rows [w*32, w*32+32) of each tile, 2 DMA instrs
    const int sseg = w * 32;
    const int srow = lane >> 2;          // 0..15 within a 16-row segment
    const int scol = (lane & 3) * 8;     // halfs (16 B chunks)

    // per-lane deferred top-2: 16 rows (mh + i*16 + quad*4 + reg)
    float sd1[16], sd2[16]; int si1[16];
    #pragma unroll
    for (int t = 0; t < 16; ++t) { sd1[t] = INFINITY; sd2[t] = INFINITY; si1[t] = 0; }

    for (int vt = 0; vt < NVT; ++vt) {
        const int v0 = vbase + vt * BV;

        floatx4 acc[4][4];
        #pragma unroll
        for (int i = 0; i < 4; ++i)
            #pragma unroll
            for (int j = 0; j < 4; ++j) acc[i][j] = (floatx4)0.0f;

        #pragma unroll 1
        for (int kt = 0; kt < EMB / BK; ++kt) {
            const size_t ko = (size_t)kt * BK + scol;
            load_lds16(zh + (size_t)(row0 + sseg + srow) * EMB + ko,      &zs[(sseg) * LW]);
            load_lds16(zh + (size_t)(row0 + sseg + 16 + srow) * EMB + ko, &zs[(sseg + 16) * LW]);
            load_lds16(ch + (size_t)(v0 + sseg + srow) * EMB + ko,        &cs[(sseg) * LW]);
            load_lds16(ch + (size_t)(v0 + sseg + 16 + srow) * EMB + ko,   &cs[(sseg + 16) * LW]);
            __syncthreads();   // compiler emits vmcnt(0) drain before barrier

            half8 a[4];
            #pragma unroll
            for (int i = 0; i < 4; ++i)
                a[i] = *(const half8*)&zs[(mh + i * 16 + lr) * LW + quad * 8];
            #pragma unroll
            for (int j = 0; j < 4; ++j) {
                const half8 b = *(const half8*)&cs[(vh + j * 16 + lr) * LW + quad * 8];
                #pragma unroll
                for (int i = 0; i < 4; ++i)
                    acc[i][j] = __builtin_amdgcn_mfma_f32_16x16x32_f16(a[i], b, acc[i][j], 0, 0, 0);
            }
            __syncthreads();
        }

        // epilogue: register-only pushes into per-lane top-2 (no cross-lane here)
        float ev[4];
        #pragma unroll
        for (int j = 0; j < 4; ++j) ev[j] = esq[v0 + vh + j * 16 + lr];
        #pragma unroll
        for (int i = 0; i < 4; ++i) {
            #pragma unroll
            for (int reg = 0; reg < 4; ++reg) {
                const int t = i * 4 + reg;
                #pragma unroll
                for (int j = 0; j < 4; ++j) {
                    const float d = ev[j] - 2.0f * acc[i][j][reg];
                    const int   v = v0 + vh + j * 16 + lr;
                    if (d < sd1[t]) { sd2[t] = sd1[t]; sd1[t] = d; si1[t] = v; }
                    else if (d < sd2[t]) { sd2[t] = d; }
                }
            }
        }
    }

    // ONE cross-lane reduce: 16 lr-lanes (same quad) share each row
    #pragma unroll
    for (int t = 0; t < 16; ++t) {
        float d1 = sd1[t], d2 = sd2[t]; int i1 = si1[t];
        #pragma unroll
        for (int off = 1; off < 16; off <<= 1) {
            const float od1 = __shfl_xor(d1, off, 64);
            const int   oi1 = __shfl_xor(i1, off, 64);
            const float od2 = __shfl_xor(d2, off, 64);
            if (od1 < d1) { d2 = fminf(d1, od2); d1 = od1; i1 = oi1; }
            else          { d2 = fminf(d2, od1); }
        }
        sd1[t] = d1; sd2[t] = d2; si1[t] = i1;
    }
    // all waves are past the kt-loop's trailing barrier -> zs reads done; alias safe
    if (lr == 0) {
        #pragma unroll
        for (int t = 0; t < 16; ++t) {
            const int r = mh + (t >> 2) * 16 + quad * 4 + (t & 3);
            sc_d1[r * 2 + (w & 1)] = sd1[t];
            sc_d2[r * 2 + (w & 1)] = sd2[t];
            sc_i1[r * 2 + (w & 1)] = si1[t];
        }
    }
    __syncthreads();
    if (tid < BM) {
        float d1 = sc_d1[tid * 2], d2 = sc_d2[tid * 2]; int i1 = sc_i1[tid * 2];
        const float od1 = sc_d1[tid * 2 + 1], od2 = sc_d2[tid * 2 + 1];
        const int   oi1 = sc_i1[tid * 2 + 1];
        if (od1 < d1) { d2 = fminf(d1, od2); d1 = od1; i1 = oi1; }
        else          { d2 = fminf(d2, od1); }
        const size_t o = (size_t)blockIdx.y * N_ROWS + row0 + tid;
        pd1[o] = d1; pi1[o] = i1; pd2[o] = d2;
    }
}

// ---------------------------------------------------------------------------
// Combine: merge VSPLIT top-2 partials; margin >= TAU -> commit, else flag.
// ---------------------------------------------------------------------------
__global__ void combine_kernel(const float* __restrict__ pd1, const int* __restrict__ pi1,
                               const float* __restrict__ pd2,
                               const float* __restrict__ cb,
                               float* __restrict__ tokens, float* __restrict__ zq,
                               float* __restrict__ cnt,
                               int* __restrict__ flagcnt, int* __restrict__ flaglist) {
    const int wave = threadIdx.x >> 6;
    const int lane = threadIdx.x & 63;
    const int row  = blockIdx.x * 4 + wave;

    float d1 = INFINITY, d2 = INFINITY; int i1 = 0;
    #pragma unroll
    for (int s = 0; s < VSPLIT; ++s) {
        const size_t o = (size_t)s * N_ROWS + row;
        const float od1 = pd1[o], od2 = pd2[o]; const int oi1 = pi1[o];
        if (od1 < d1) { d2 = fminf(d1, od2); d1 = od1; i1 = oi1; }
        else          { d2 = fminf(d2, od1); }
    }
    if ((d2 - d1) < TAU) {
        if (lane == 0) {
            const int pos = atomicAdd(flagcnt, 1);
            flaglist[pos] = row;
        }
        return;   // rescue path writes this row
    }
    if (lane == 0) {
        tokens[row] = (float)i1;
        atomicAdd(&cnt[i1], 1.0f);
    }
    const float4 v = *(const float4*)(cb + (size_t)i1 * EMB + lane * 4);
    *(float4*)(zq + (size_t)row * EMB + lane * 4) = v;
}

// ---------------------------------------------------------------------------
// Rescue: exact fp32 argmin for flagged rows. Job = (row, 128-code chunk);
// 4 waves/block x 32 codes; coalesced 1 KB reads; packed-key atomicMin merge.
// ---------------------------------------------------------------------------
__global__ void rescue2_kernel(const int* __restrict__ flagcnt, const int* __restrict__ flaglist,
                               const float* __restrict__ z, const float* __restrict__ cb,
                               const float* __restrict__ esq,
                               unsigned long long* __restrict__ rkey) {
    const int tid  = threadIdx.x;
    const int w    = tid >> 6;
    const int lane = tid & 63;
    const int n = *flagcnt;
    const int njobs = n * 64;
    for (int j = blockIdx.x; j < njobs; j += gridDim.x) {
        const int row = flaglist[j >> 6];
        const int v0  = (j & 63) * 128 + w * 32;
        const float4 zl4 = *(const float4*)(z + (size_t)row * EMB + lane * 4);
        float bd = INFINITY; int bv = 0;
        #pragma unroll 4
        for (int c = 0; c < 32; ++c) {
            const int v = v0 + c;
            const float4 cv = *(const float4*)(cb + (size_t)v * EMB + lane * 4);
            float p = zl4.x * cv.x + zl4.y * cv.y + zl4.z * cv.z + zl4.w * cv.w;
            #pragma unroll
            for (int off = 32; off > 0; off >>= 1) p += __shfl_down(p, off, 64);
            if (lane == 0) {
                const float d = esq[v] - 2.0f * p;
                if (d < bd) { bd = d; bv = v; }   // v ascending: lowest tie index
            }
        }
        if (lane == 0) {
            unsigned int u = __float_as_uint(bd);
            u = (u & 0x80000000u) ? ~u : (u | 0x80000000u);   // order-preserving map
            const unsigned long long key =
                ((unsigned long long)u << 32) | (unsigned int)bv;
            atomicMin(rkey + row, key);
        }
    }
}

__global__ void rescue_write_kernel(const int* __restrict__ flagcnt,
                                    const int* __restrict__ flaglist,
                                    const unsigned long long* __restrict__ rkey,
                                    const float* __restrict__ cb,
                                    float* __restrict__ tokens, float* __restrict__ zq,
                                    float* __restrict__ cnt) {
    const int w    = threadIdx.x >> 6;
    const int lane = threadIdx.x & 63;
    const int n = *flagcnt;
    for (int f = blockIdx.x * 4 + w; f < n; f += gridDim.x * 4) {
        const int row = flaglist[f];
        const int v = (int)(unsigned int)(rkey[row] & 0xFFFFFFFFull);
        if (lane == 0) {
            tokens[row] = (float)v;
            atomicAdd(&cnt[v], 1.0f);
        }
        const float4 c4 = *(const float4*)(cb + (size_t)v * EMB + lane * 4);
        *(float4*)(zq + (size_t)row * EMB + lane * 4) = c4;
    }
}

// ===========================================================================
// Fallback (round-3 fp32 path) if ws is too small.
// ===========================================================================
#define FLSTR 36
__global__ __launch_bounds__(256, 2)
void fb_dist_kernel(const float* __restrict__ z, const float* __restrict__ cb,
                    const float* __restrict__ esq,
                    float* __restrict__ pdist, int* __restrict__ pidx) {
    __shared__ float zs[BM][FLSTR];
    __shared__ float es[BV][FLSTR];
    __shared__ float rdist[16][16];
    __shared__ int   ridx [16][16];
    const int row0 = blockIdx.x * BM, vbase = blockIdx.y * VRANGE;
    const int tid = threadIdx.x, wave = tid >> 6, lane = tid & 63;
    const int wly = (lane >> 3) & 7, wlx = lane & 7;
    const int wbase = (wave >> 1) * 64, cbase = (wave & 1) * 64;
    const int arow = wbase + wly, bcol = cbase + wlx;
    const int rowSlot = (wave >> 1) * 8 + wly, colSlot = (wave & 1) * 8 + wlx;
    const int sc4 = tid & 7, sr0 = tid >> 3;
    float best[8]; int bidx[8];
    #pragma unroll
    for (int i = 0; i < 8; ++i) { best[i] = INFINITY; bidx[i] = 0; }
    for (int vt = 0; vt < NVT; ++vt) {
        const int v0 = vbase + vt * BV;
        float acc[8][8];
        #pragma unroll
        for (int i = 0; i < 8; ++i)
            #pragma unroll
            for (int j = 0; j < 8; ++j) acc[i][j] = 0.0f;
        #pragma unroll 1
        for (int kt = 0; kt < EMB / 32; ++kt) {
            #pragma unroll
            for (int t = 0; t < 4; ++t) {
                const int r = sr0 + 32 * t;
                *(float4*)&zs[r][sc4 * 4] = *(const float4*)(z  + (size_t)(row0 + r) * EMB + kt * 32 + sc4 * 4);
                *(float4*)&es[r][sc4 * 4] = *(const float4*)(cb + (size_t)(v0 + r) * EMB + kt * 32 + sc4 * 4);
            }
            __syncthreads();
            #pragma unroll 1
            for (int k0 = 0; k0 < 8; ++k0) {
                const int kk = k0 * 4;
                float a[8][4];
                #pragma unroll
                for (int i = 0; i < 8; ++i) {
                    const float4 a4 = *(const float4*)&zs[arow + 8 * i][kk];
                    a[i][0] = a4.x; a[i][1] = a4.y; a[i][2] = a4.z; a[i][3] = a4.w;
                }
                #pragma unroll
                for (int j = 0; j < 8; ++j) {
                    const float4 b4 = *(const float4*)&es[bcol + 8 * j][kk];
                    #pragma unroll
                    for (int i = 0; i < 8; ++i) {
                        acc[i][j] += a[i][0] * b4.x; acc[i][j] += a[i][1] * b4.y;
                        acc[i][j] += a[i][2] * b4.z; acc[i][j] += a[i][3] * b4.w;
                    }
                }
            }
            __syncthreads();
        }
        #pragma unroll
        for (int j = 0; j < 8; ++j) {
            const int v = v0 + bcol + 8 * j;
            const float evv = esq[v];
            #pragma unroll
            for (int i = 0; i < 8; ++i) {
                const float d = evv - 2.0f * acc[i][j];
                if (d < best[i]) { best[i] = d; bidx[i] = v; }
            }
        }
    }
    for (int i = 0; i < 8; ++i) {
        rdist[rowSlot][colSlot] = best[i];
        ridx [rowSlot][colSlot] = bidx[i];
        __syncthreads();
        if (colSlot == 0) {
            float bd = rdist[rowSlot][0]; int bi = ridx[rowSlot][0];
            #pragma unroll
            for (int t = 1; t < 16; ++t) {
                const float d = rdist[rowSlot][t]; const int ii = ridx[rowSlot][t];
                if (d < bd || (d == bd && ii < bi)) { bd = d; bi = ii; }
            }
            const int row = row0 + wbase + 8 * i + wly;
            pdist[(size_t)blockIdx.y * N_ROWS + row] = bd;
            pidx [(size_t)blockIdx.y * N_ROWS + row] = bi;
        }
        __syncthreads();
    }
}

__global__ void fb_combine_kernel(const float* __restrict__ pdist, const int* __restrict__ pidx,
                                  const float* __restrict__ cb,
                                  float* __restrict__ tokens, float* __restrict__ zq,
                                  float* __restrict__ cnt) {
    const int wave = threadIdx.x >> 6, lane = threadIdx.x & 63;
    const int row = blockIdx.x * 4 + wave;
    float bd = INFINITY; int bi = 0;
    #pragma unroll
    for (int s = 0; s < VSPLIT; ++s) {
        const float d = pdist[(size_t)s * N_ROWS + row];
        const int ii  = pidx [(size_t)s * N_ROWS + row];
        if (d < bd || (d == bd && ii < bi)) { bd = d; bi = ii; }
    }
    if (lane == 0) { tokens[row] = (float)bi; atomicAdd(&cnt[bi], 1.0f); }
    const float4 v = *(const float4*)(cb + (size_t)bi * EMB + lane * 4);
    *(float4*)(zq + (size_t)row * EMB + lane * 4) = v;
}

// ---------------------------------------------------------------------------
// d_out: [0,N) tokens | [N, N+N*EMB) zq | +VOCAB ref_count
// ws: zh (8 MB) | ch (4 MB) | esq | pd1|pd2 | pi1 | rkey | flagcnt | flaglist
// ---------------------------------------------------------------------------
extern "C" void kernel_launch(void* const* d_in, const int* in_sizes, int n_in,
                              void* d_out, int out_size, void* d_ws, size_t ws_size,
                              hipStream_t stream) {
    const float* z  = (const float*)d_in[0];
    const float* cb = (const float*)d_in[1];

    float* out    = (float*)d_out;
    float* tokens = out;
    float* zq     = out + N_ROWS;
    float* cnt    = out + N_ROWS + (size_t)N_ROWS * EMB;

    hipMemsetAsync(cnt, 0, VOCAB * sizeof(float), stream);

    const size_t ZE = (size_t)N_ROWS * EMB, CE = (size_t)VOCAB * EMB, P = (size_t)VSPLIT * N_ROWS;
    const size_t NEED = (ZE + CE) * sizeof(_Float16) + VOCAB * 4
                      + 3 * P * 4 + (size_t)N_ROWS * 8 + 16 + N_ROWS * 4 + 256;

    if (ws_size >= NEED) {
        char* p = (char*)d_ws;
        _Float16* zh = (_Float16*)p;            p += ZE * 2;
        _Float16* ch = (_Float16*)p;            p += CE * 2;
        float* esq   = (float*)p;               p += VOCAB * 4;
        float* pd1   = (float*)p;               p += P * 4;
        float* pd2   = (float*)p;               p += P * 4;
        int*   pi1   = (int*)p;                 p += P * 4;
        unsigned long long* rkey = (unsigned long long*)p;  p += (size_t)N_ROWS * 8;
        int*   flagcnt = (int*)p;               p += 16;
        int*   flaglist = (int*)p;

        hipMemsetAsync(flagcnt, 0, sizeof(int), stream);
        hipMemsetAsync(rkey, 0xFF, (size_t)N_ROWS * 8, stream);   // +inf keys

        esq_kernel<<<VOCAB / 4, 256, 0, stream>>>(cb, esq);
        split_kernel<<<(int)((ZE + CE) / 4 / 256), 256, 0, stream>>>(z, cb, zh, ch);
        mfma_dist_kernel<<<dim3(N_ROWS / BM, VSPLIT), 256, 0, stream>>>(
            zh, ch, esq, pd1, pi1, pd2);
        combine_kernel<<<N_ROWS / 4, 256, 0, stream>>>(
            pd1, pi1, pd2, cb, tokens, zq, cnt, flagcnt, flaglist);
        rescue2_kernel<<<1024, 256, 0, stream>>>(flagcnt, flaglist, z, cb, esq, rkey);
        rescue_write_kernel<<<32, 256, 0, stream>>>(flagcnt, flaglist, rkey, cb, tokens, zq, cnt);
    } else {
        float* esq   = (float*)d_ws;
        float* pdist = esq + VOCAB;
        int*   pidx  = (int*)(pdist + P);
        esq_kernel<<<VOCAB / 4, 256, 0, stream>>>(cb, esq);
        fb_dist_kernel<<<dim3(N_ROWS / BM, VSPLIT), 256, 0, stream>>>(z, cb, esq, pdist, pidx);
        fb_combine_kernel<<<N_ROWS / 4, 256, 0, stream>>>(pdist, pidx, cb, tokens, zq, cnt);
    }
}

// Round 7
// 342.299 us; speedup vs baseline: 1.3055x; 1.3055x over previous
//
#include <hip/hip_runtime.h>
#include <math.h>

#define N_ROWS 16384
#define VOCAB  8192
#define EMB    256

// ---- MFMA path tiling (m97-shaped: 128x128 tile, BK=32, 4x4 acc/wave) ----
#define BM 128
#define BV 128
#define BK 32                      // halfs per K-step
#define VSPLIT 8                   // grid (128, 8)
#define VRANGE (VOCAB / VSPLIT)    // 1024
#define NVT    (VRANGE / BV)       // 8
#define LW 32                      // LDS row stride in halfs (64 B) — UNPADDED (global_load_lds)
#define TAU 0.15f                  // rescue margin: >= 2*max|dist err| (~0.107 at 4.2 sigma)

typedef _Float16 half8 __attribute__((ext_vector_type(8)));
typedef _Float16 half4 __attribute__((ext_vector_type(4)));
typedef float floatx4 __attribute__((ext_vector_type(4)));

// async global->LDS DMA, 16 B/lane; LDS dest = wave-uniform base + lane*16
__device__ __forceinline__ void load_lds16(const _Float16* g, _Float16* l) {
    __builtin_amdgcn_global_load_lds(
        (const __attribute__((address_space(1))) void*)g,
        (__attribute__((address_space(3))) void*)l, 16, 0, 0);
}

// ---------------------------------------------------------------------------
// esq[v] = ||cb[v]||^2 (fp32, exact). One wave per row.
// ---------------------------------------------------------------------------
__global__ void esq_kernel(const float* __restrict__ cb, float* __restrict__ esq) {
    const int wave = threadIdx.x >> 6;
    const int lane = threadIdx.x & 63;
    const int row  = blockIdx.x * 4 + wave;
    const float4 v = *(const float4*)(cb + (size_t)row * EMB + lane * 4);
    float s = v.x * v.x + v.y * v.y + v.z * v.z + v.w * v.w;
    #pragma unroll
    for (int off = 32; off > 0; off >>= 1) s += __shfl_down(s, off, 64);
    if (lane == 0) esq[row] = s;
}

// ---------------------------------------------------------------------------
// Convert fp32 -> fp16 (single precision level; rescue covers the error).
// ---------------------------------------------------------------------------
__global__ void split_kernel(const float* __restrict__ z, const float* __restrict__ cb,
                             _Float16* __restrict__ zh, _Float16* __restrict__ ch) {
    const size_t gid = (size_t)blockIdx.x * blockDim.x + threadIdx.x;
    const size_t ZQ4 = (size_t)N_ROWS * EMB / 4;
    const float* src; _Float16* dst; size_t idx4;
    if (gid < ZQ4) { src = z;  dst = zh; idx4 = gid; }
    else           { src = cb; dst = ch; idx4 = gid - ZQ4; }
    const float4 f = *(const float4*)(src + idx4 * 4);
    half4 h;
    h.x = (_Float16)f.x; h.y = (_Float16)f.y; h.z = (_Float16)f.z; h.w = (_Float16)f.w;
    *(half4*)(dst + idx4 * 4) = h;
}

// ---------------------------------------------------------------------------
// MFMA dist kernel, single fp16 term: acc = Zh*Ch^T; dist~ = esq - 2*acc.
// (unchanged from round 6 — rescue was the measured bottleneck)
// ---------------------------------------------------------------------------
__global__ __launch_bounds__(256, 3)
void mfma_dist_kernel(const _Float16* __restrict__ zh, const _Float16* __restrict__ ch,
                      const float* __restrict__ esq,
                      float* __restrict__ pd1, int* __restrict__ pi1,
                      float* __restrict__ pd2) {
    __shared__ _Float16 zs[BM * LW];   // 8 KB
    __shared__ _Float16 cs[BV * LW];   // 8 KB
    float* sc_d1 = (float*)zs;                 // [BM][2] end-phase alias
    float* sc_d2 = sc_d1 + BM * 2;
    int*   sc_i1 = (int*)(sc_d2 + BM * 2);

    const int row0  = blockIdx.x * BM;
    const int vbase = blockIdx.y * VRANGE;

    const int tid  = threadIdx.x;
    const int w    = tid >> 6;
    const int lane = tid & 63;
    const int lr   = lane & 15;
    const int quad = lane >> 4;
    const int mh   = (w >> 1) * 64;
    const int vh   = (w & 1) * 64;

    const int sseg = w * 32;
    const int srow = lane >> 2;
    const int scol = (lane & 3) * 8;

    float sd1[16], sd2[16]; int si1[16];
    #pragma unroll
    for (int t = 0; t < 16; ++t) { sd1[t] = INFINITY; sd2[t] = INFINITY; si1[t] = 0; }

    for (int vt = 0; vt < NVT; ++vt) {
        const int v0 = vbase + vt * BV;

        floatx4 acc[4][4];
        #pragma unroll
        for (int i = 0; i < 4; ++i)
            #pragma unroll
            for (int j = 0; j < 4; ++j) acc[i][j] = (floatx4)0.0f;

        #pragma unroll 1
        for (int kt = 0; kt < EMB / BK; ++kt) {
            const size_t ko = (size_t)kt * BK + scol;
            load_lds16(zh + (size_t)(row0 + sseg + srow) * EMB + ko,      &zs[(sseg) * LW]);
            load_lds16(zh + (size_t)(row0 + sseg + 16 + srow) * EMB + ko, &zs[(sseg + 16) * LW]);
            load_lds16(ch + (size_t)(v0 + sseg + srow) * EMB + ko,        &cs[(sseg) * LW]);
            load_lds16(ch + (size_t)(v0 + sseg + 16 + srow) * EMB + ko,   &cs[(sseg + 16) * LW]);
            __syncthreads();

            half8 a[4];
            #pragma unroll
            for (int i = 0; i < 4; ++i)
                a[i] = *(const half8*)&zs[(mh + i * 16 + lr) * LW + quad * 8];
            #pragma unroll
            for (int j = 0; j < 4; ++j) {
                const half8 b = *(const half8*)&cs[(vh + j * 16 + lr) * LW + quad * 8];
                #pragma unroll
                for (int i = 0; i < 4; ++i)
                    acc[i][j] = __builtin_amdgcn_mfma_f32_16x16x32_f16(a[i], b, acc[i][j], 0, 0, 0);
            }
            __syncthreads();
        }

        float ev[4];
        #pragma unroll
        for (int j = 0; j < 4; ++j) ev[j] = esq[v0 + vh + j * 16 + lr];
        #pragma unroll
        for (int i = 0; i < 4; ++i) {
            #pragma unroll
            for (int reg = 0; reg < 4; ++reg) {
                const int t = i * 4 + reg;
                #pragma unroll
                for (int j = 0; j < 4; ++j) {
                    const float d = ev[j] - 2.0f * acc[i][j][reg];
                    const int   v = v0 + vh + j * 16 + lr;
                    if (d < sd1[t]) { sd2[t] = sd1[t]; sd1[t] = d; si1[t] = v; }
                    else if (d < sd2[t]) { sd2[t] = d; }
                }
            }
        }
    }

    #pragma unroll
    for (int t = 0; t < 16; ++t) {
        float d1 = sd1[t], d2 = sd2[t]; int i1 = si1[t];
        #pragma unroll
        for (int off = 1; off < 16; off <<= 1) {
            const float od1 = __shfl_xor(d1, off, 64);
            const int   oi1 = __shfl_xor(i1, off, 64);
            const float od2 = __shfl_xor(d2, off, 64);
            if (od1 < d1) { d2 = fminf(d1, od2); d1 = od1; i1 = oi1; }
            else          { d2 = fminf(d2, od1); }
        }
        sd1[t] = d1; sd2[t] = d2; si1[t] = i1;
    }
    if (lr == 0) {
        #pragma unroll
        for (int t = 0; t < 16; ++t) {
            const int r = mh + (t >> 2) * 16 + quad * 4 + (t & 3);
            sc_d1[r * 2 + (w & 1)] = sd1[t];
            sc_d2[r * 2 + (w & 1)] = sd2[t];
            sc_i1[r * 2 + (w & 1)] = si1[t];
        }
    }
    __syncthreads();
    if (tid < BM) {
        float d1 = sc_d1[tid * 2], d2 = sc_d2[tid * 2]; int i1 = sc_i1[tid * 2];
        const float od1 = sc_d1[tid * 2 + 1], od2 = sc_d2[tid * 2 + 1];
        const int   oi1 = sc_i1[tid * 2 + 1];
        if (od1 < d1) { d2 = fminf(d1, od2); d1 = od1; i1 = oi1; }
        else          { d2 = fminf(d2, od1); }
        const size_t o = (size_t)blockIdx.y * N_ROWS + row0 + tid;
        pd1[o] = d1; pi1[o] = i1; pd2[o] = d2;
    }
}

// ---------------------------------------------------------------------------
// Combine: merge VSPLIT top-2 partials; margin >= TAU -> commit, else flag.
// ---------------------------------------------------------------------------
__global__ void combine_kernel(const float* __restrict__ pd1, const int* __restrict__ pi1,
                               const float* __restrict__ pd2,
                               const float* __restrict__ cb,
                               float* __restrict__ tokens, float* __restrict__ zq,
                               float* __restrict__ cnt,
                               int* __restrict__ flagcnt, int* __restrict__ flaglist) {
    const int wave = threadIdx.x >> 6;
    const int lane = threadIdx.x & 63;
    const int row  = blockIdx.x * 4 + wave;

    float d1 = INFINITY, d2 = INFINITY; int i1 = 0;
    #pragma unroll
    for (int s = 0; s < VSPLIT; ++s) {
        const size_t o = (size_t)s * N_ROWS + row;
        const float od1 = pd1[o], od2 = pd2[o]; const int oi1 = pi1[o];
        if (od1 < d1) { d2 = fminf(d1, od2); d1 = od1; i1 = oi1; }
        else          { d2 = fminf(d2, od1); }
    }
    if ((d2 - d1) < TAU) {
        if (lane == 0) {
            const int pos = atomicAdd(flagcnt, 1);
            flaglist[pos] = row;
        }
        return;   // rescue path writes this row
    }
    if (lane == 0) {
        tokens[row] = (float)i1;
        atomicAdd(&cnt[i1], 1.0f);
    }
    const float4 v = *(const float4*)(cb + (size_t)i1 * EMB + lane * 4);
    *(float4*)(zq + (size_t)row * EMB + lane * 4) = v;
}

// ---------------------------------------------------------------------------
// Rescue v3: exact fp32 argmin for flagged rows.
// Job = (row, 32-code chunk) per WAVE. Within a wave: 4 lanes per code x 16
// codes in parallel -> 16 indep float4 loads + 64 FMAs per lane, then a
// 2-deep shuffle reduce shared by 16 codes (vs 6-deep per code before).
// Wave revisits the same 32 KB chunk across rows (j-stride = 0 mod 256)
// -> chunk stays cache-hot. Packed-key atomicMin merges across waves.
// ---------------------------------------------------------------------------
__global__ void rescue3_kernel(const int* __restrict__ flagcnt, const int* __restrict__ flaglist,
                               const float* __restrict__ z, const float* __restrict__ cb,
                               const float* __restrict__ esq,
                               unsigned long long* __restrict__ rkey) {
    const int tid  = threadIdx.x;
    const int w    = tid >> 6;
    const int lane = tid & 63;
    const int g    = lane >> 2;        // code group 0..15
    const int s    = lane & 3;         // sub-lane 0..3 (64 dims each)
    const int n = *flagcnt;
    const int waveId = blockIdx.x * 4 + w;
    const int nwaves = gridDim.x * 4;
    const int njobs  = n * 256;        // 256 chunks of 32 codes per row
    for (int j = waveId; j < njobs; j += nwaves) {
        const int row = flaglist[j >> 8];
        const int c0  = (j & 255) * 32;
        const float* zr = z + (size_t)row * EMB;
        float bd = INFINITY; int bv = 0;
        #pragma unroll
        for (int gs = 0; gs < 2; ++gs) {
            const int v = c0 + gs * 16 + g;
            const float* cr = cb + (size_t)v * EMB;
            float p = 0.0f;
            #pragma unroll
            for (int k = 0; k < 16; ++k) {
                const float4 c4 = *(const float4*)(cr + k * 16 + s * 4);
                const float4 z4 = *(const float4*)(zr + k * 16 + s * 4);
                p += z4.x * c4.x + z4.y * c4.y + z4.z * c4.z + z4.w * c4.w;
            }
            p += __shfl_xor(p, 1, 64);
            p += __shfl_xor(p, 2, 64);          // all 4 lanes of group hold full dot
            const float d = esq[v] - 2.0f * p;
            if (d < bd || (d == bd && v < bv)) { bd = d; bv = v; }
        }
        // merge the 16 groups (lanes within a group are identical)
        #pragma unroll
        for (int off = 4; off < 64; off <<= 1) {
            const float od = __shfl_xor(bd, off, 64);
            const int   ov = __shfl_xor(bv, off, 64);
            if (od < bd || (od == bd && ov < bv)) { bd = od; bv = ov; }
        }
        if (lane == 0) {
            unsigned int u = __float_as_uint(bd);
            u = (u & 0x80000000u) ? ~u : (u | 0x80000000u);   // order-preserving map
            const unsigned long long key =
                ((unsigned long long)u << 32) | (unsigned int)bv;
            atomicMin(rkey + row, key);
        }
    }
}

__global__ void rescue_write_kernel(const int* __restrict__ flagcnt,
                                    const int* __restrict__ flaglist,
                                    const unsigned long long* __restrict__ rkey,
                                    const float* __restrict__ cb,
                                    float* __restrict__ tokens, float* __restrict__ zq,
                                    float* __restrict__ cnt) {
    const int w    = threadIdx.x >> 6;
    const int lane = threadIdx.x & 63;
    const int n = *flagcnt;
    for (int f = blockIdx.x * 4 + w; f < n; f += gridDim.x * 4) {
        const int row = flaglist[f];
        const int v = (int)(unsigned int)(rkey[row] & 0xFFFFFFFFull);
        if (lane == 0) {
            tokens[row] = (float)v;
            atomicAdd(&cnt[v], 1.0f);
        }
        const float4 c4 = *(const float4*)(cb + (size_t)v * EMB + lane * 4);
        *(float4*)(zq + (size_t)row * EMB + lane * 4) = c4;
    }
}

// ===========================================================================
// Fallback (round-3 fp32 path) if ws is too small.
// ===========================================================================
#define FLSTR 36
__global__ __launch_bounds__(256, 2)
void fb_dist_kernel(const float* __restrict__ z, const float* __restrict__ cb,
                    const float* __restrict__ esq,
                    float* __restrict__ pdist, int* __restrict__ pidx) {
    __shared__ float zs[BM][FLSTR];
    __shared__ float es[BV][FLSTR];
    __shared__ float rdist[16][16];
    __shared__ int   ridx [16][16];
    const int row0 = blockIdx.x * BM, vbase = blockIdx.y * VRANGE;
    const int tid = threadIdx.x, wave = tid >> 6, lane = tid & 63;
    const int wly = (lane >> 3) & 7, wlx = lane & 7;
    const int wbase = (wave >> 1) * 64, cbase = (wave & 1) * 64;
    const int arow = wbase + wly, bcol = cbase + wlx;
    const int rowSlot = (wave >> 1) * 8 + wly, colSlot = (wave & 1) * 8 + wlx;
    const int sc4 = tid & 7, sr0 = tid >> 3;
    float best[8]; int bidx[8];
    #pragma unroll
    for (int i = 0; i < 8; ++i) { best[i] = INFINITY; bidx[i] = 0; }
    for (int vt = 0; vt < NVT; ++vt) {
        const int v0 = vbase + vt * BV;
        float acc[8][8];
        #pragma unroll
        for (int i = 0; i < 8; ++i)
            #pragma unroll
            for (int j = 0; j < 8; ++j) acc[i][j] = 0.0f;
        #pragma unroll 1
        for (int kt = 0; kt < EMB / 32; ++kt) {
            #pragma unroll
            for (int t = 0; t < 4; ++t) {
                const int r = sr0 + 32 * t;
                *(float4*)&zs[r][sc4 * 4] = *(const float4*)(z  + (size_t)(row0 + r) * EMB + kt * 32 + sc4 * 4);
                *(float4*)&es[r][sc4 * 4] = *(const float4*)(cb + (size_t)(v0 + r) * EMB + kt * 32 + sc4 * 4);
            }
            __syncthreads();
            #pragma unroll 1
            for (int k0 = 0; k0 < 8; ++k0) {
                const int kk = k0 * 4;
                float a[8][4];
                #pragma unroll
                for (int i = 0; i < 8; ++i) {
                    const float4 a4 = *(const float4*)&zs[arow + 8 * i][kk];
                    a[i][0] = a4.x; a[i][1] = a4.y; a[i][2] = a4.z; a[i][3] = a4.w;
                }
                #pragma unroll
                for (int j = 0; j < 8; ++j) {
                    const float4 b4 = *(const float4*)&es[bcol + 8 * j][kk];
                    #pragma unroll
                    for (int i = 0; i < 8; ++i) {
                        acc[i][j] += a[i][0] * b4.x; acc[i][j] += a[i][1] * b4.y;
                        acc[i][j] += a[i][2] * b4.z; acc[i][j] += a[i][3] * b4.w;
                    }
                }
            }
            __syncthreads();
        }
        #pragma unroll
        for (int j = 0; j < 8; ++j) {
            const int v = v0 + bcol + 8 * j;
            const float evv = esq[v];
            #pragma unroll
            for (int i = 0; i < 8; ++i) {
                const float d = evv - 2.0f * acc[i][j];
                if (d < best[i]) { best[i] = d; bidx[i] = v; }
            }
        }
    }
    for (int i = 0; i < 8; ++i) {
        rdist[rowSlot][colSlot] = best[i];
        ridx [rowSlot][colSlot] = bidx[i];
        __syncthreads();
        if (colSlot == 0) {
            float bd = rdist[rowSlot][0]; int bi = ridx[rowSlot][0];
            #pragma unroll
            for (int t = 1; t < 16; ++t) {
                const float d = rdist[rowSlot][t]; const int ii = ridx[rowSlot][t];
                if (d < bd || (d == bd && ii < bi)) { bd = d; bi = ii; }
            }
            const int row = row0 + wbase + 8 * i + wly;
            pdist[(size_t)blockIdx.y * N_ROWS + row] = bd;
            pidx [(size_t)blockIdx.y * N_ROWS + row] = bi;
        }
        __syncthreads();
    }
}

__global__ void fb_combine_kernel(const float* __restrict__ pdist, const int* __restrict__ pidx,
                                  const float* __restrict__ cb,
                                  float* __restrict__ tokens, float* __restrict__ zq,
                                  float* __restrict__ cnt) {
    const int wave = threadIdx.x >> 6, lane = threadIdx.x & 63;
    const int row = blockIdx.x * 4 + wave;
    float bd = INFINITY; int bi = 0;
    #pragma unroll
    for (int s = 0; s < VSPLIT; ++s) {
        const float d = pdist[(size_t)s * N_ROWS + row];
        const int ii  = pidx [(size_t)s * N_ROWS + row];
        if (d < bd || (d == bd && ii < bi)) { bd = d; bi = ii; }
    }
    if (lane == 0) { tokens[row] = (float)bi; atomicAdd(&cnt[bi], 1.0f); }
    const float4 v = *(const float4*)(cb + (size_t)bi * EMB + lane * 4);
    *(float4*)(zq + (size_t)row * EMB + lane * 4) = v;
}

// ---------------------------------------------------------------------------
// d_out: [0,N) tokens | [N, N+N*EMB) zq | +VOCAB ref_count
// ws: zh (8 MB) | ch (4 MB) | esq | pd1|pd2 | pi1 | rkey | flagcnt | flaglist
// ---------------------------------------------------------------------------
extern "C" void kernel_launch(void* const* d_in, const int* in_sizes, int n_in,
                              void* d_out, int out_size, void* d_ws, size_t ws_size,
                              hipStream_t stream) {
    const float* z  = (const float*)d_in[0];
    const float* cb = (const float*)d_in[1];

    float* out    = (float*)d_out;
    float* tokens = out;
    float* zq     = out + N_ROWS;
    float* cnt    = out + N_ROWS + (size_t)N_ROWS * EMB;

    hipMemsetAsync(cnt, 0, VOCAB * sizeof(float), stream);

    const size_t ZE = (size_t)N_ROWS * EMB, CE = (size_t)VOCAB * EMB, P = (size_t)VSPLIT * N_ROWS;
    const size_t NEED = (ZE + CE) * sizeof(_Float16) + VOCAB * 4
                      + 3 * P * 4 + (size_t)N_ROWS * 8 + 16 + N_ROWS * 4 + 256;

    if (ws_size >= NEED) {
        char* p = (char*)d_ws;
        _Float16* zh = (_Float16*)p;            p += ZE * 2;
        _Float16* ch = (_Float16*)p;            p += CE * 2;
        float* esq   = (float*)p;               p += VOCAB * 4;
        float* pd1   = (float*)p;               p += P * 4;
        float* pd2   = (float*)p;               p += P * 4;
        int*   pi1   = (int*)p;                 p += P * 4;
        unsigned long long* rkey = (unsigned long long*)p;  p += (size_t)N_ROWS * 8;
        int*   flagcnt = (int*)p;               p += 16;
        int*   flaglist = (int*)p;

        hipMemsetAsync(flagcnt, 0, sizeof(int), stream);
        hipMemsetAsync(rkey, 0xFF, (size_t)N_ROWS * 8, stream);   // +inf keys

        esq_kernel<<<VOCAB / 4, 256, 0, stream>>>(cb, esq);
        split_kernel<<<(int)((ZE + CE) / 4 / 256), 256, 0, stream>>>(z, cb, zh, ch);
        mfma_dist_kernel<<<dim3(N_ROWS / BM, VSPLIT), 256, 0, stream>>>(
            zh, ch, esq, pd1, pi1, pd2);
        combine_kernel<<<N_ROWS / 4, 256, 0, stream>>>(
            pd1, pi1, pd2, cb, tokens, zq, cnt, flagcnt, flaglist);
        rescue3_kernel<<<2048, 256, 0, stream>>>(flagcnt, flaglist, z, cb, esq, rkey);
        rescue_write_kernel<<<32, 256, 0, stream>>>(flagcnt, flaglist, rkey, cb, tokens, zq, cnt);
    } else {
        float* esq   = (float*)d_ws;
        float* pdist = esq + VOCAB;
        int*   pidx  = (int*)(pdist + P);
        esq_kernel<<<VOCAB / 4, 256, 0, stream>>>(cb, esq);
        fb_dist_kernel<<<dim3(N_ROWS / BM, VSPLIT), 256, 0, stream>>>(z, cb, esq, pdist, pidx);
        fb_combine_kernel<<<N_ROWS / 4, 256, 0, stream>>>(pdist, pidx, cb, tokens, zq, cnt);
    }
}